// Round 1
// baseline (659.789 us; speedup 1.0000x reference)
//
#include <hip/hip_runtime.h>
#include <cstdint>
#include <cstddef>

// Problem dims (fixed by setup_inputs)
#define B_  8
#define S_  4096
#define D_  1024
#define H_  1024
#define M_  (B_*S_)          // 32768 GEMM rows
#define NC_ 16               // scan chunks
#define L_  (S_/NC_)         // 256 steps per chunk

typedef __bf16 bf16x8 __attribute__((ext_vector_type(8)));
typedef float  f32x4  __attribute__((ext_vector_type(4)));
typedef uint16_t u16x8 __attribute__((ext_vector_type(8)));

__device__ __forceinline__ uint16_t f2bf(float f) {
  union { float f; uint32_t u; } v; v.f = f;
  uint32_t u = v.u;
  u += 0x7FFFu + ((u >> 16) & 1u);   // RNE
  return (uint16_t)(u >> 16);
}
__device__ __forceinline__ float bf2f(uint16_t h) {
  union { uint32_t u; float f; } v; v.u = ((uint32_t)h) << 16;
  return v.f;
}
__device__ __forceinline__ float gfun(float x) {
  // g(x) = x+0.5 if x>=0 else sigmoid(x)
  return x >= 0.0f ? x + 0.5f : 1.0f / (1.0f + __expf(-x));
}

// ---------------- fp32 -> bf16 convert (8 elems/thread) ----------------
__global__ __launch_bounds__(256) void cvt_kernel(const float* __restrict__ in,
                                                  uint16_t* __restrict__ out,
                                                  int n8) {
  int i = blockIdx.x * 256 + threadIdx.x;
  if (i >= n8) return;
  const float4* p = (const float4*)in;
  float4 a = p[2 * i], b = p[2 * i + 1];
  u16x8 v;
  v[0] = f2bf(a.x); v[1] = f2bf(a.y); v[2] = f2bf(a.z); v[3] = f2bf(a.w);
  v[4] = f2bf(b.x); v[5] = f2bf(b.y); v[6] = f2bf(b.z); v[7] = f2bf(b.w);
  *(u16x8*)&out[8 * i] = v;
}

// ---------------- bf16 GEMM: Out(M,N) = A(M,K) @ Bw(N,K)^T + bias ----------------
// 128x128 tile, BK=64, 4 waves (each a 64x64 quadrant of 4x4 16x16x32 MFMAs).
// Staging via global_load_lds width 16. LDS layout XOR-swizzled on the global
// gather side: 16B unit u holds tile element (row r=u>>3, col-unit (u&7)^(r&7)).
#define BM 128
#define BN 128
#define BK 64
__global__ __launch_bounds__(256)
void gemm_bias_bf16_kernel(const uint16_t* __restrict__ A,
                           const uint16_t* __restrict__ Bw,
                           const float* __restrict__ bias,
                           uint16_t* __restrict__ Out,
                           int M, int N, int K) {
  __shared__ __attribute__((aligned(16))) uint16_t As[BM * BK];
  __shared__ __attribute__((aligned(16))) uint16_t Bs[BN * BK];
  const int tid  = threadIdx.x;
  const int lane = tid & 63;
  const int wave = tid >> 6;
  const int mTile = blockIdx.y * BM;
  const int nTile = blockIdx.x * BN;
  const int wm0 = (wave >> 1) * 64;
  const int wn0 = (wave & 1) * 64;
  const int q  = lane >> 4;     // quad 0..3
  const int mn = lane & 15;     // m (A) / n (B) within 16-tile

  f32x4 acc[4][4] = {};

  for (int kt = 0; kt < K; kt += BK) {
    __syncthreads();   // previous iter's LDS reads done before overwrite
    // Stage A tile: 1024 16B-units, 256 lanes x 16B x 4 issues.
    #pragma unroll
    for (int i = 0; i < 4; i++) {
      int u = i * 256 + tid;
      int r = u >> 3;
      int c = (u & 7) ^ (r & 7);
      const uint16_t* gp = A + (size_t)(mTile + r) * K + kt + c * 8;
      __builtin_amdgcn_global_load_lds(
          (const __attribute__((address_space(1))) void*)gp,
          (__attribute__((address_space(3))) void*)&As[(i * 256 + wave * 64) * 8],
          16, 0, 0);
    }
    #pragma unroll
    for (int i = 0; i < 4; i++) {
      int u = i * 256 + tid;
      int r = u >> 3;
      int c = (u & 7) ^ (r & 7);
      const uint16_t* gp = Bw + (size_t)(nTile + r) * K + kt + c * 8;
      __builtin_amdgcn_global_load_lds(
          (const __attribute__((address_space(1))) void*)gp,
          (__attribute__((address_space(3))) void*)&Bs[(i * 256 + wave * 64) * 8],
          16, 0, 0);
    }
    __syncthreads();   // drains vmcnt (global_load_lds) + lgkm

    #pragma unroll
    for (int s = 0; s < 2; s++) {     // two k=32 MFMA steps per BK=64 tile
      bf16x8 av[4], bv[4];
      #pragma unroll
      for (int tm = 0; tm < 4; tm++) {
        int r = wm0 + tm * 16 + mn;
        int cu = s * 4 + q;
        int unit = r * 8 + (cu ^ (r & 7));
        av[tm] = *(const bf16x8*)&As[unit * 8];
      }
      #pragma unroll
      for (int tn = 0; tn < 4; tn++) {
        int r = wn0 + tn * 16 + mn;
        int cu = s * 4 + q;
        int unit = r * 8 + (cu ^ (r & 7));
        bv[tn] = *(const bf16x8*)&Bs[unit * 8];
      }
      #pragma unroll
      for (int tm = 0; tm < 4; tm++)
        #pragma unroll
        for (int tn = 0; tn < 4; tn++)
          acc[tm][tn] = __builtin_amdgcn_mfma_f32_16x16x32_bf16(
              av[tm], bv[tn], acc[tm][tn], 0, 0, 0);
    }
  }

  // Epilogue: D col=lane&15, row=quad*4+reg (m89/m91). Add bias, store bf16.
  #pragma unroll
  for (int tn = 0; tn < 4; tn++) {
    int col = nTile + wn0 + tn * 16 + mn;
    float bb = bias[col];
    #pragma unroll
    for (int tm = 0; tm < 4; tm++) {
      int row0 = mTile + wm0 + tm * 16 + q * 4;
      #pragma unroll
      for (int i = 0; i < 4; i++) {
        Out[(size_t)(row0 + i) * N + col] = f2bf(acc[tm][tn][i] + bb);
      }
    }
  }
}

// ---------------- scan pass 1: per-chunk (C, V) composition ----------------
__global__ __launch_bounds__(256) void scan_chunk_kernel(
    const uint16_t* __restrict__ kb, const uint16_t* __restrict__ gb,
    float* __restrict__ Cc, float* __restrict__ Vc) {
  int h  = blockIdx.x * 256 + threadIdx.x;
  int nc = blockIdx.y, b = blockIdx.z;
  size_t base = ((size_t)(b * S_ + nc * L_)) * H_ + h;
  float C = 1.0f, V = 0.0f;
  #pragma unroll 4
  for (int i = 0; i < L_; i++) {
    float kf = bf2f(kb[base + (size_t)i * H_]);
    float gf = bf2f(gb[base + (size_t)i * H_]);
    float c = 1.0f / (1.0f + __expf(kf));    // sigmoid(-k)
    float z = 1.0f / (1.0f + __expf(-kf));   // sigmoid(k)
    float v = z * gfun(gf);
    C *= c;
    V = c * V + v;
  }
  Cc[(size_t)(b * NC_ + nc) * H_ + h] = C;
  Vc[(size_t)(b * NC_ + nc) * H_ + h] = V;
}

// ---------------- scan pass 2: prefix over chunk states ----------------
__global__ __launch_bounds__(256) void chunk_prefix_kernel(
    const float* __restrict__ Cc, const float* __restrict__ Vc,
    const float* __restrict__ h0, float* __restrict__ Hin) {
  int h = blockIdx.x * 256 + threadIdx.x;
  int b = blockIdx.y;
  float Hv = gfun(h0[(size_t)b * H_ + h]);   // H state entering chunk 0
  Hin[(size_t)(b * NC_) * H_ + h] = Hv;
  #pragma unroll
  for (int nc = 1; nc < NC_; nc++) {
    size_t idx = (size_t)(b * NC_ + nc - 1) * H_ + h;
    Hv = Cc[idx] * Hv + Vc[idx];
    Hin[(size_t)(b * NC_ + nc) * H_ + h] = Hv;
  }
}

// ---------------- scan pass 3: apply with true carry-in, write h ----------------
__global__ __launch_bounds__(256) void scan_apply_kernel(
    const uint16_t* __restrict__ kb, const uint16_t* __restrict__ gb,
    const float* __restrict__ Hin, float* __restrict__ out) {
  int h  = blockIdx.x * 256 + threadIdx.x;
  int nc = blockIdx.y, b = blockIdx.z;
  size_t base = ((size_t)(b * S_ + nc * L_)) * H_ + h;
  float Hv = Hin[(size_t)(b * NC_ + nc) * H_ + h];
  #pragma unroll 4
  for (int i = 0; i < L_; i++) {
    float kf = bf2f(kb[base + (size_t)i * H_]);
    float gf = bf2f(gb[base + (size_t)i * H_]);
    float c = 1.0f / (1.0f + __expf(kf));
    float z = 1.0f / (1.0f + __expf(-kf));
    float v = z * gfun(gf);
    Hv = c * Hv + v;
    out[base + (size_t)i * H_] = Hv;
  }
}

extern "C" void kernel_launch(void* const* d_in, const int* in_sizes, int n_in,
                              void* d_out, int out_size, void* d_ws, size_t ws_size,
                              hipStream_t stream) {
  const float* x  = (const float*)d_in[0];
  const float* h0 = (const float*)d_in[1];
  const float* Wz = (const float*)d_in[2];
  const float* bz = (const float*)d_in[3];
  const float* Wh = (const float*)d_in[4];
  const float* bh = (const float*)d_in[5];
  float* out = (float*)d_out;

  // Workspace layout (~196 MB total)
  char* ws = (char*)d_ws;
  uint16_t* xb  = (uint16_t*)ws; ws += (size_t)M_ * D_ * 2;     // 64 MB
  uint16_t* Wzb = (uint16_t*)ws; ws += (size_t)H_ * D_ * 2;     // 2 MB
  uint16_t* Whb = (uint16_t*)ws; ws += (size_t)H_ * D_ * 2;     // 2 MB
  uint16_t* kb  = (uint16_t*)ws; ws += (size_t)M_ * H_ * 2;     // 64 MB
  uint16_t* gb  = (uint16_t*)ws; ws += (size_t)M_ * H_ * 2;     // 64 MB
  float* Cc  = (float*)ws; ws += (size_t)B_ * NC_ * H_ * 4;     // 512 KB
  float* Vc  = (float*)ws; ws += (size_t)B_ * NC_ * H_ * 4;     // 512 KB
  float* Hin = (float*)ws; ws += (size_t)B_ * NC_ * H_ * 4;     // 512 KB

  // 1) convert inputs to bf16
  cvt_kernel<<<dim3((M_ * D_ / 8 + 255) / 256), 256, 0, stream>>>(x, xb, M_ * D_ / 8);
  cvt_kernel<<<dim3((H_ * D_ / 8 + 255) / 256), 256, 0, stream>>>(Wz, Wzb, H_ * D_ / 8);
  cvt_kernel<<<dim3((H_ * D_ / 8 + 255) / 256), 256, 0, stream>>>(Wh, Whb, H_ * D_ / 8);

  // 2) two GEMMs -> raw preactivations k, p (bf16)
  dim3 ggrid(H_ / BN, M_ / BM);   // (8, 256)
  gemm_bias_bf16_kernel<<<ggrid, 256, 0, stream>>>(xb, Wzb, bz, kb, M_, H_, D_);
  gemm_bias_bf16_kernel<<<ggrid, 256, 0, stream>>>(xb, Whb, bh, gb, M_, H_, D_);

  // 3-5) chunked linear scan
  scan_chunk_kernel<<<dim3(H_ / 256, NC_, B_), 256, 0, stream>>>(kb, gb, Cc, Vc);
  chunk_prefix_kernel<<<dim3(H_ / 256, B_), 256, 0, stream>>>(Cc, Vc, h0, Hin);
  scan_apply_kernel<<<dim3(H_ / 256, NC_, B_), 256, 0, stream>>>(kb, gb, Hin, out);
}

// Round 2
// 481.671 us; speedup vs baseline: 1.3698x; 1.3698x over previous
//
#include <hip/hip_runtime.h>
#include <cstdint>
#include <cstddef>

// Problem dims (fixed by setup_inputs)
#define B_  8
#define S_  4096
#define D_  1024
#define H_  1024
#define M_  (B_*S_)          // 32768 GEMM rows
#define NC_ 64               // scan chunks
#define L_  (S_/NC_)         // 64 steps per chunk

typedef __bf16 bf16x8 __attribute__((ext_vector_type(8)));
typedef float  f32x4  __attribute__((ext_vector_type(4)));
typedef uint16_t u16x8 __attribute__((ext_vector_type(8)));

__device__ __forceinline__ uint16_t f2bf(float f) {
  union { float f; uint32_t u; } v; v.f = f;
  uint32_t u = v.u;
  u += 0x7FFFu + ((u >> 16) & 1u);   // RNE
  return (uint16_t)(u >> 16);
}
__device__ __forceinline__ float gfun(float x) {
  // g(x) = x+0.5 if x>=0 else sigmoid(x)
  return x >= 0.0f ? x + 0.5f
                   : __builtin_amdgcn_rcpf(1.0f + __expf(-x));
}
__device__ __forceinline__ void unpack_cv(uint32_t u, float& c, float& v) {
  union { uint32_t u; _Float16 h[2]; } p; p.u = u;
  c = (float)p.h[0]; v = (float)p.h[1];
}

// ---------------- fp32 -> bf16 convert (8 elems/thread) ----------------
__global__ __launch_bounds__(256) void cvt_kernel(const float* __restrict__ in,
                                                  uint16_t* __restrict__ out,
                                                  int n8) {
  int i = blockIdx.x * 256 + threadIdx.x;
  if (i >= n8) return;
  const float4* p = (const float4*)in;
  float4 a = p[2 * i], b = p[2 * i + 1];
  u16x8 v;
  v[0] = f2bf(a.x); v[1] = f2bf(a.y); v[2] = f2bf(a.z); v[3] = f2bf(a.w);
  v[4] = f2bf(b.x); v[5] = f2bf(b.y); v[6] = f2bf(b.z); v[7] = f2bf(b.w);
  *(u16x8*)&out[8 * i] = v;
}

// ---------------- fused dual GEMM + activation epilogue ----------------
// Block: 128 rows x 64 cols of BOTH k = x@Wz^T+bz and p = x@Wh^T+bh.
// Wave: 64x32 of each (4m x 2n 16x16x32 MFMA tiles, two acc sets).
// Epilogue: c = sigmoid(-k), v = sigmoid(k)*g(p), packed (c,v) fp16 pair.
#define BM 128
#define BNH 64
#define BK 64
__global__ __launch_bounds__(256)
void fused_gemm_kernel(const uint16_t* __restrict__ A,
                       const uint16_t* __restrict__ Wz,
                       const uint16_t* __restrict__ Wh,
                       const float* __restrict__ bz,
                       const float* __restrict__ bh,
                       uint32_t* __restrict__ cv) {
  __shared__ __attribute__((aligned(16))) uint16_t As[BM * BK];    // 16 KB
  __shared__ __attribute__((aligned(16))) uint16_t Bzs[BNH * BK];  // 8 KB
  __shared__ __attribute__((aligned(16))) uint16_t Bhs[BNH * BK];  // 8 KB
  const int tid  = threadIdx.x;
  const int lane = tid & 63;
  const int wave = tid >> 6;
  const int mTile = blockIdx.y * BM;
  const int nTile = blockIdx.x * BNH;
  const int wm0 = (wave >> 1) * 64;
  const int wn0 = (wave & 1) * 32;
  const int q  = lane >> 4;     // quad 0..3
  const int mn = lane & 15;

  f32x4 accK[4][2] = {};
  f32x4 accP[4][2] = {};

  for (int kt = 0; kt < D_; kt += BK) {
    __syncthreads();
    // A tile: 1024 16B-units (XOR-swizzled on the gather side)
    #pragma unroll
    for (int i = 0; i < 4; i++) {
      int u = i * 256 + tid;
      int r = u >> 3;
      int c = (u & 7) ^ (r & 7);
      __builtin_amdgcn_global_load_lds(
          (const __attribute__((address_space(1))) void*)(A + (size_t)(mTile + r) * D_ + kt + c * 8),
          (__attribute__((address_space(3))) void*)&As[(i * 256 + wave * 64) * 8],
          16, 0, 0);
    }
    // Wz tile: 512 units
    #pragma unroll
    for (int i = 0; i < 2; i++) {
      int u = i * 256 + tid;
      int r = u >> 3;
      int c = (u & 7) ^ (r & 7);
      __builtin_amdgcn_global_load_lds(
          (const __attribute__((address_space(1))) void*)(Wz + (size_t)(nTile + r) * D_ + kt + c * 8),
          (__attribute__((address_space(3))) void*)&Bzs[(i * 256 + wave * 64) * 8],
          16, 0, 0);
    }
    // Wh tile: 512 units
    #pragma unroll
    for (int i = 0; i < 2; i++) {
      int u = i * 256 + tid;
      int r = u >> 3;
      int c = (u & 7) ^ (r & 7);
      __builtin_amdgcn_global_load_lds(
          (const __attribute__((address_space(1))) void*)(Wh + (size_t)(nTile + r) * D_ + kt + c * 8),
          (__attribute__((address_space(3))) void*)&Bhs[(i * 256 + wave * 64) * 8],
          16, 0, 0);
    }
    __syncthreads();

    #pragma unroll
    for (int s = 0; s < 2; s++) {
      bf16x8 av[4], bzv[2], bhv[2];
      const int cu = s * 4 + q;
      #pragma unroll
      for (int tm = 0; tm < 4; tm++) {
        int r = wm0 + tm * 16 + mn;
        av[tm] = *(const bf16x8*)&As[(r * 8 + (cu ^ (r & 7))) * 8];
      }
      #pragma unroll
      for (int tn = 0; tn < 2; tn++) {
        int r = wn0 + tn * 16 + mn;
        int unit = r * 8 + (cu ^ (r & 7));
        bzv[tn] = *(const bf16x8*)&Bzs[unit * 8];
        bhv[tn] = *(const bf16x8*)&Bhs[unit * 8];
      }
      #pragma unroll
      for (int tm = 0; tm < 4; tm++)
        #pragma unroll
        for (int tn = 0; tn < 2; tn++) {
          accK[tm][tn] = __builtin_amdgcn_mfma_f32_16x16x32_bf16(
              av[tm], bzv[tn], accK[tm][tn], 0, 0, 0);
          accP[tm][tn] = __builtin_amdgcn_mfma_f32_16x16x32_bf16(
              av[tm], bhv[tn], accP[tm][tn], 0, 0, 0);
        }
    }
  }

  // Epilogue: D col=lane&15, row=quad*4+reg. Both k and p live in-lane.
  #pragma unroll
  for (int tn = 0; tn < 2; tn++) {
    int col = nTile + wn0 + tn * 16 + mn;
    float bzc = bz[col], bhc = bh[col];
    #pragma unroll
    for (int tm = 0; tm < 4; tm++) {
      int row0 = mTile + wm0 + tm * 16 + q * 4;
      #pragma unroll
      for (int i = 0; i < 4; i++) {
        float kv = accK[tm][tn][i] + bzc;
        float pv = accP[tm][tn][i] + bhc;
        float c = __builtin_amdgcn_rcpf(1.0f + __expf(kv));   // sigmoid(-k)
        float z = 1.0f - c;                                    // sigmoid(k)
        float v = z * gfun(pv);
        union { _Float16 h[2]; uint32_t u; } pk;
        pk.h[0] = (_Float16)c; pk.h[1] = (_Float16)v;
        cv[(size_t)(row0 + i) * H_ + col] = pk.u;
      }
    }
  }
}

// ---------------- scan pass 1: per-chunk (C, V) composition ----------------
// Thread handles 4 consecutive h channels; 16 B uint4 loads.
__global__ __launch_bounds__(256) void scan_chunk_kernel(
    const uint32_t* __restrict__ cv, float4* __restrict__ Cc,
    float4* __restrict__ Vc) {
  const int tid = threadIdx.x;                 // h0 = tid*4
  const int nc = blockIdx.x, b = blockIdx.y;
  const uint4* cv4 = (const uint4*)cv;
  size_t base = (size_t)(b * S_ + nc * L_) * (H_ / 4) + tid;
  float C[4] = {1.f, 1.f, 1.f, 1.f};
  float V[4] = {0.f, 0.f, 0.f, 0.f};
  #pragma unroll 4
  for (int t = 0; t < L_; t++) {
    uint4 w = cv4[base + (size_t)t * (H_ / 4)];
    float c, v;
    unpack_cv(w.x, c, v); C[0] *= c; V[0] = c * V[0] + v;
    unpack_cv(w.y, c, v); C[1] *= c; V[1] = c * V[1] + v;
    unpack_cv(w.z, c, v); C[2] *= c; V[2] = c * V[2] + v;
    unpack_cv(w.w, c, v); C[3] *= c; V[3] = c * V[3] + v;
  }
  size_t o = (size_t)(b * NC_ + nc) * (H_ / 4) + tid;
  Cc[o] = (float4){C[0], C[1], C[2], C[3]};
  Vc[o] = (float4){V[0], V[1], V[2], V[3]};
}

// ---------------- scan pass 2: prefix over chunk states ----------------
__global__ __launch_bounds__(256) void chunk_prefix_kernel(
    const float* __restrict__ Cc, const float* __restrict__ Vc,
    const float* __restrict__ h0, float* __restrict__ Hin) {
  int h = blockIdx.x * 256 + threadIdx.x;
  int b = blockIdx.y;
  float Hv = gfun(h0[(size_t)b * H_ + h]);
  Hin[(size_t)(b * NC_) * H_ + h] = Hv;
  #pragma unroll 8
  for (int nc = 1; nc < NC_; nc++) {
    size_t idx = (size_t)(b * NC_ + nc - 1) * H_ + h;
    Hv = Cc[idx] * Hv + Vc[idx];
    Hin[(size_t)(b * NC_ + nc) * H_ + h] = Hv;
  }
}

// ---------------- scan pass 3: apply with carry-in, write fp32 h ----------------
__global__ __launch_bounds__(256) void scan_apply_kernel(
    const uint32_t* __restrict__ cv, const float4* __restrict__ Hin,
    float4* __restrict__ out) {
  const int tid = threadIdx.x;
  const int nc = blockIdx.x, b = blockIdx.y;
  const uint4* cv4 = (const uint4*)cv;
  size_t base = (size_t)(b * S_ + nc * L_) * (H_ / 4) + tid;
  float4 Hq = Hin[(size_t)(b * NC_ + nc) * (H_ / 4) + tid];
  float Hr[4] = {Hq.x, Hq.y, Hq.z, Hq.w};
  #pragma unroll 4
  for (int t = 0; t < L_; t++) {
    size_t idx = base + (size_t)t * (H_ / 4);
    uint4 w = cv4[idx];
    float c, v;
    unpack_cv(w.x, c, v); Hr[0] = c * Hr[0] + v;
    unpack_cv(w.y, c, v); Hr[1] = c * Hr[1] + v;
    unpack_cv(w.z, c, v); Hr[2] = c * Hr[2] + v;
    unpack_cv(w.w, c, v); Hr[3] = c * Hr[3] + v;
    out[idx] = (float4){Hr[0], Hr[1], Hr[2], Hr[3]};
  }
}

extern "C" void kernel_launch(void* const* d_in, const int* in_sizes, int n_in,
                              void* d_out, int out_size, void* d_ws, size_t ws_size,
                              hipStream_t stream) {
  const float* x  = (const float*)d_in[0];
  const float* h0 = (const float*)d_in[1];
  const float* Wz = (const float*)d_in[2];
  const float* bz = (const float*)d_in[3];
  const float* Wh = (const float*)d_in[4];
  const float* bh = (const float*)d_in[5];
  float* out = (float*)d_out;

  // Workspace layout (~202 MB): xb is dead after the GEMM, so the small
  // scan-state buffers alias its region.
  char* ws = (char*)d_ws;
  uint16_t* xb  = (uint16_t*)ws; ws += (size_t)M_ * D_ * 2;     // 64 MB
  uint16_t* Wzb = (uint16_t*)ws; ws += (size_t)H_ * D_ * 2;     // 2 MB
  uint16_t* Whb = (uint16_t*)ws; ws += (size_t)H_ * D_ * 2;     // 2 MB
  uint32_t* cvb = (uint32_t*)ws; ws += (size_t)M_ * H_ * 4;     // 134 MB
  char* alias = (char*)xb;
  float* Cc  = (float*)alias; alias += (size_t)B_ * NC_ * H_ * 4;  // 2 MB
  float* Vc  = (float*)alias; alias += (size_t)B_ * NC_ * H_ * 4;  // 2 MB
  float* Hin = (float*)alias; alias += (size_t)B_ * NC_ * H_ * 4;  // 2 MB

  // 1) convert inputs to bf16
  cvt_kernel<<<dim3(M_ * D_ / 8 / 256), 256, 0, stream>>>(x, xb, M_ * D_ / 8);
  cvt_kernel<<<dim3(H_ * D_ / 8 / 256), 256, 0, stream>>>(Wz, Wzb, H_ * D_ / 8);
  cvt_kernel<<<dim3(H_ * D_ / 8 / 256), 256, 0, stream>>>(Wh, Whb, H_ * D_ / 8);

  // 2) fused dual GEMM + activation -> packed (c,v) fp16 pairs
  fused_gemm_kernel<<<dim3(H_ / BNH, M_ / BM), 256, 0, stream>>>(
      xb, Wzb, Whb, bz, bh, cvb);

  // 3-5) chunked linear scan (pure FMA now)
  scan_chunk_kernel<<<dim3(NC_, B_), 256, 0, stream>>>(cvb, (float4*)Cc, (float4*)Vc);
  chunk_prefix_kernel<<<dim3(H_ / 256, B_), 256, 0, stream>>>(Cc, Vc, h0, Hin);
  scan_apply_kernel<<<dim3(NC_, B_), 256, 0, stream>>>(cvb, (const float4*)Hin, (float4*)out);
}

// Round 3
// 442.600 us; speedup vs baseline: 1.4907x; 1.0883x over previous
//
#include <hip/hip_runtime.h>
#include <cstdint>
#include <cstddef>

// Problem dims (fixed by setup_inputs)
#define B_  8
#define S_  4096
#define D_  1024
#define H_  1024
#define M_  (B_*S_)          // 32768 GEMM rows
#define NC_ 64               // scan chunks
#define L_  (S_/NC_)         // 64 steps per chunk

typedef __bf16 bf16x8 __attribute__((ext_vector_type(8)));
typedef float  f32x4  __attribute__((ext_vector_type(4)));
typedef uint16_t u16x8 __attribute__((ext_vector_type(8)));

__device__ __forceinline__ uint16_t f2bf(float f) {
  union { float f; uint32_t u; } v; v.f = f;
  uint32_t u = v.u;
  u += 0x7FFFu + ((u >> 16) & 1u);   // RNE
  return (uint16_t)(u >> 16);
}
__device__ __forceinline__ float gfun(float x) {
  // g(x) = x+0.5 if x>=0 else sigmoid(x)
  return x >= 0.0f ? x + 0.5f
                   : __builtin_amdgcn_rcpf(1.0f + __expf(-x));
}
__device__ __forceinline__ void unpack_cv(uint32_t u, float& c, float& v) {
  union { uint32_t u; _Float16 h[2]; } p; p.u = u;
  c = (float)p.h[0]; v = (float)p.h[1];
}

// ---------------- fused fp32 -> bf16 convert for x, Wz, Wh ----------------
#define X8_  (M_ * D_ / 8)
#define W8_  (H_ * D_ / 8)
#define TOT8_ (X8_ + 2 * W8_)
__global__ __launch_bounds__(256) void cvt_all_kernel(
    const float* __restrict__ x, const float* __restrict__ Wz,
    const float* __restrict__ Wh, uint16_t* __restrict__ xb,
    uint16_t* __restrict__ Wzb, uint16_t* __restrict__ Whb) {
  int stride = gridDim.x * 256;
  for (int u = blockIdx.x * 256 + threadIdx.x; u < TOT8_; u += stride) {
    const float* src; uint16_t* dst;
    if (u < X8_)            { src = x  + (size_t)u * 8;          dst = xb  + (size_t)u * 8; }
    else if (u < X8_ + W8_) { size_t v = u - X8_;        src = Wz + v * 8; dst = Wzb + v * 8; }
    else                    { size_t v = u - X8_ - W8_;  src = Wh + v * 8; dst = Whb + v * 8; }
    float4 a = ((const float4*)src)[0], b = ((const float4*)src)[1];
    u16x8 o;
    o[0] = f2bf(a.x); o[1] = f2bf(a.y); o[2] = f2bf(a.z); o[3] = f2bf(a.w);
    o[4] = f2bf(b.x); o[5] = f2bf(b.y); o[6] = f2bf(b.z); o[7] = f2bf(b.w);
    *(u16x8*)dst = o;
  }
}

// ---------------- fused dual GEMM + activation epilogue ----------------
// Block: 128 rows x 128 cols of BOTH k = x@Wz^T+bz and p = x@Wh^T+bh.
// 4 waves in 2x2; wave tile 64x64 per gemm (4m x 4n 16x16x32 MFMAs, dual acc).
// Epilogue: c = sigmoid(-k), v = sigmoid(k)*g(p), packed (c,v) fp16 pair.
#define BM 128
#define BNH 128
#define BK 64
__global__ __launch_bounds__(256, 2)
void fused_gemm_kernel(const uint16_t* __restrict__ A,
                       const uint16_t* __restrict__ Wz,
                       const uint16_t* __restrict__ Wh,
                       const float* __restrict__ bz,
                       const float* __restrict__ bh,
                       uint32_t* __restrict__ cv) {
  __shared__ __attribute__((aligned(16))) uint16_t As[BM * BK];    // 16 KB
  __shared__ __attribute__((aligned(16))) uint16_t Bzs[BNH * BK];  // 16 KB
  __shared__ __attribute__((aligned(16))) uint16_t Bhs[BNH * BK];  // 16 KB
  const int tid  = threadIdx.x;
  const int lane = tid & 63;
  const int wave = tid >> 6;
  const int mTile = blockIdx.y * BM;
  const int nTile = blockIdx.x * BNH;
  const int wm0 = (wave >> 1) * 64;
  const int wn0 = (wave & 1) * 64;
  const int q  = lane >> 4;     // quad 0..3
  const int mn = lane & 15;

  // Hoisted staging addresses: unit u = i*256 + tid; row r = u>>3,
  // col-unit (u&7)^(r&7) (XOR swizzle applied on the gather side).
  const uint16_t* aPtr[4];
  const uint16_t* zPtr[4];
  const uint16_t* hPtr[4];
  #pragma unroll
  for (int i = 0; i < 4; i++) {
    int u = i * 256 + tid;
    int r = u >> 3;
    int c = (u & 7) ^ (r & 7);
    aPtr[i] = A  + (size_t)(mTile + r) * D_ + c * 8;
    zPtr[i] = Wz + (size_t)(nTile + r) * D_ + c * 8;
    hPtr[i] = Wh + (size_t)(nTile + r) * D_ + c * 8;
  }
  const int ldsDst = (wave * 64 + lane) * 8;   // element offset of this lane's 16B slot

  f32x4 accK[4][4] = {};
  f32x4 accP[4][4] = {};

  for (int kt = 0; kt < D_; kt += BK) {
    __syncthreads();
    #pragma unroll
    for (int i = 0; i < 4; i++)
      __builtin_amdgcn_global_load_lds(
          (const __attribute__((address_space(1))) void*)(aPtr[i] + kt),
          (__attribute__((address_space(3))) void*)&As[i * 2048 + ldsDst], 16, 0, 0);
    #pragma unroll
    for (int i = 0; i < 4; i++)
      __builtin_amdgcn_global_load_lds(
          (const __attribute__((address_space(1))) void*)(zPtr[i] + kt),
          (__attribute__((address_space(3))) void*)&Bzs[i * 2048 + ldsDst], 16, 0, 0);
    #pragma unroll
    for (int i = 0; i < 4; i++)
      __builtin_amdgcn_global_load_lds(
          (const __attribute__((address_space(1))) void*)(hPtr[i] + kt),
          (__attribute__((address_space(3))) void*)&Bhs[i * 2048 + ldsDst], 16, 0, 0);
    __syncthreads();

    #pragma unroll
    for (int s = 0; s < 2; s++) {
      bf16x8 av[4], bzv[4], bhv[4];
      const int cu = s * 4 + q;
      #pragma unroll
      for (int tm = 0; tm < 4; tm++) {
        int r = wm0 + tm * 16 + mn;
        av[tm] = *(const bf16x8*)&As[(r * 8 + (cu ^ (r & 7))) * 8];
      }
      #pragma unroll
      for (int tn = 0; tn < 4; tn++) {
        int r = wn0 + tn * 16 + mn;
        int unit = r * 8 + (cu ^ (r & 7));
        bzv[tn] = *(const bf16x8*)&Bzs[unit * 8];
        bhv[tn] = *(const bf16x8*)&Bhs[unit * 8];
      }
      #pragma unroll
      for (int tm = 0; tm < 4; tm++)
        #pragma unroll
        for (int tn = 0; tn < 4; tn++) {
          accK[tm][tn] = __builtin_amdgcn_mfma_f32_16x16x32_bf16(
              av[tm], bzv[tn], accK[tm][tn], 0, 0, 0);
          accP[tm][tn] = __builtin_amdgcn_mfma_f32_16x16x32_bf16(
              av[tm], bhv[tn], accP[tm][tn], 0, 0, 0);
        }
    }
  }

  // Epilogue: D col=lane&15, row=quad*4+reg. Both k and p live in-lane.
  #pragma unroll
  for (int tn = 0; tn < 4; tn++) {
    int col = nTile + wn0 + tn * 16 + mn;
    float bzc = bz[col], bhc = bh[col];
    #pragma unroll
    for (int tm = 0; tm < 4; tm++) {
      int row0 = mTile + wm0 + tm * 16 + q * 4;
      #pragma unroll
      for (int i = 0; i < 4; i++) {
        float kv = accK[tm][tn][i] + bzc;
        float pv = accP[tm][tn][i] + bhc;
        float c = __builtin_amdgcn_rcpf(1.0f + __expf(kv));   // sigmoid(-k)
        float z = 1.0f - c;                                    // sigmoid(k)
        float v = z * gfun(pv);
        union { _Float16 h[2]; uint32_t u; } pk;
        pk.h[0] = (_Float16)c; pk.h[1] = (_Float16)v;
        cv[(size_t)(row0 + i) * H_ + col] = pk.u;
      }
    }
  }
}

// ---------------- scan pass 1: per-chunk (C, V) composition ----------------
__global__ __launch_bounds__(256) void scan_chunk_kernel(
    const uint32_t* __restrict__ cv, float4* __restrict__ Cc,
    float4* __restrict__ Vc) {
  const int tid = threadIdx.x;                 // channels tid*4..tid*4+3
  const int nc = blockIdx.x, b = blockIdx.y;
  const uint4* cv4 = (const uint4*)cv;
  size_t base = (size_t)(b * S_ + nc * L_) * (H_ / 4) + tid;
  float C[4] = {1.f, 1.f, 1.f, 1.f};
  float V[4] = {0.f, 0.f, 0.f, 0.f};
  #pragma unroll 4
  for (int t = 0; t < L_; t++) {
    uint4 w = cv4[base + (size_t)t * (H_ / 4)];
    float c, v;
    unpack_cv(w.x, c, v); C[0] *= c; V[0] = c * V[0] + v;
    unpack_cv(w.y, c, v); C[1] *= c; V[1] = c * V[1] + v;
    unpack_cv(w.z, c, v); C[2] *= c; V[2] = c * V[2] + v;
    unpack_cv(w.w, c, v); C[3] *= c; V[3] = c * V[3] + v;
  }
  size_t o = (size_t)(b * NC_ + nc) * (H_ / 4) + tid;
  Cc[o] = (float4){C[0], C[1], C[2], C[3]};
  Vc[o] = (float4){V[0], V[1], V[2], V[3]};
}

// ---------------- scan pass 2: apply with inline carry-in prefix ----------------
__global__ __launch_bounds__(256) void scan_apply_kernel(
    const uint32_t* __restrict__ cv, const float4* __restrict__ Cc,
    const float4* __restrict__ Vc, const float* __restrict__ h0,
    float4* __restrict__ out) {
  const int tid = threadIdx.x;
  const int nc = blockIdx.x, b = blockIdx.y;
  const uint4* cv4 = (const uint4*)cv;

  // Carry-in: H = g(h0), then compose chunk states 0..nc-1 (small, L2-hot).
  float Hr[4];
  #pragma unroll
  for (int j = 0; j < 4; j++) Hr[j] = gfun(h0[(size_t)b * H_ + tid * 4 + j]);
  #pragma unroll 4
  for (int j = 0; j < nc; j++) {
    size_t idx = (size_t)(b * NC_ + j) * (H_ / 4) + tid;
    float4 Cq = Cc[idx], Vq = Vc[idx];
    Hr[0] = Cq.x * Hr[0] + Vq.x;
    Hr[1] = Cq.y * Hr[1] + Vq.y;
    Hr[2] = Cq.z * Hr[2] + Vq.z;
    Hr[3] = Cq.w * Hr[3] + Vq.w;
  }

  size_t base = (size_t)(b * S_ + nc * L_) * (H_ / 4) + tid;
  #pragma unroll 4
  for (int t = 0; t < L_; t++) {
    size_t idx = base + (size_t)t * (H_ / 4);
    uint4 w = cv4[idx];
    float c, v;
    unpack_cv(w.x, c, v); Hr[0] = c * Hr[0] + v;
    unpack_cv(w.y, c, v); Hr[1] = c * Hr[1] + v;
    unpack_cv(w.z, c, v); Hr[2] = c * Hr[2] + v;
    unpack_cv(w.w, c, v); Hr[3] = c * Hr[3] + v;
    out[idx] = (float4){Hr[0], Hr[1], Hr[2], Hr[3]};
  }
}

extern "C" void kernel_launch(void* const* d_in, const int* in_sizes, int n_in,
                              void* d_out, int out_size, void* d_ws, size_t ws_size,
                              hipStream_t stream) {
  const float* x  = (const float*)d_in[0];
  const float* h0 = (const float*)d_in[1];
  const float* Wz = (const float*)d_in[2];
  const float* bz = (const float*)d_in[3];
  const float* Wh = (const float*)d_in[4];
  const float* bh = (const float*)d_in[5];
  float* out = (float*)d_out;

  // Workspace layout (~202 MB): xb is dead after the GEMM; scan chunk-state
  // buffers alias its region.
  char* ws = (char*)d_ws;
  uint16_t* xb  = (uint16_t*)ws; ws += (size_t)M_ * D_ * 2;     // 64 MB
  uint16_t* Wzb = (uint16_t*)ws; ws += (size_t)H_ * D_ * 2;     // 2 MB
  uint16_t* Whb = (uint16_t*)ws; ws += (size_t)H_ * D_ * 2;     // 2 MB
  uint32_t* cvb = (uint32_t*)ws; ws += (size_t)M_ * H_ * 4;     // 134 MB
  char* alias = (char*)xb;
  float* Cc  = (float*)alias; alias += (size_t)B_ * NC_ * H_ * 4;  // 2 MB
  float* Vc  = (float*)alias; alias += (size_t)B_ * NC_ * H_ * 4;  // 2 MB

  // 1) convert x, Wz, Wh to bf16 (single kernel)
  cvt_all_kernel<<<dim3(2048), 256, 0, stream>>>(x, Wz, Wh, xb, Wzb, Whb);

  // 2) fused dual GEMM + activation -> packed (c,v) fp16 pairs
  fused_gemm_kernel<<<dim3(H_ / BNH, M_ / BM), 256, 0, stream>>>(
      xb, Wzb, Whb, bz, bh, cvb);

  // 3-4) chunked linear scan
  scan_chunk_kernel<<<dim3(NC_, B_), 256, 0, stream>>>(cvb, (float4*)Cc, (float4*)Vc);
  scan_apply_kernel<<<dim3(NC_, B_), 256, 0, stream>>>(
      cvb, (const float4*)Cc, (const float4*)Vc, h0, (float4*)out);
}